// Round 4
// baseline (6046.725 us; speedup 1.0000x reference)
//
#include <hip/hip_runtime.h>
#include <hip/hip_bf16.h>
#include <stdint.h>

#define TT 1024
#define DD 512
#define HH 512

typedef short bf16x8 __attribute__((ext_vector_type(8)));
typedef float f32x4 __attribute__((ext_vector_type(4)));
typedef unsigned long long u64;
typedef u64 u64x2 __attribute__((ext_vector_type(2)));
typedef unsigned int u32;
typedef unsigned short u16;

// ---- workspace layout (bytes) ----
#define OFF_WPACK 0ull
#define SZ_WPACK  (32ull*4*4*8*1024)       // 4 MiB B-fragments
#define OFF_XS    (OFF_WPACK + SZ_WPACK)    // 64 MiB x A-fragment blob
#define SZ_XS     (1024ull*65536)
#define OFF_HBUF  (OFF_XS + SZ_XS)          // 2 x 64 KiB h A-fragment blobs
#define SZ_HBUF   (2ull*65536)
#define OFF_FLAGS (OFF_HBUF + SZ_HBUF)      // 128 per-wave flags, packed (512 B)

__device__ __forceinline__ u16 f2bf(float f){
  u32 u = __builtin_bit_cast(u32, f);
  u32 r = (u + 0x7fffu + ((u >> 16) & 1u)) >> 16;   // RNE
  return (u16)r;
}

__global__ void k_init_flags(int* flags){
  flags[threadIdx.x] = -1;                 // 128 threads
}

// ---- pack Wcat=[Wx;Wh] into B-fragment order (verified r0-r3) ----
__global__ void k_pack_w(const float* __restrict__ Wx, const float* __restrict__ Wh,
                         u16* __restrict__ wp){
  int id = blockIdx.x * 256 + threadIdx.x;        // 262144
  int lane = id & 63;
  int kk = (id >> 6) & 7, n = (id >> 9) & 3, q = (id >> 11) & 3, w = id >> 13;
  int col = n * 512 + w * 16 + (lane & 15);
  int kb  = q * 256 + kk * 32 + (lane >> 4) * 8;
  union { u16 v[8]; uint4 u; } pk;
#pragma unroll
  for (int j = 0; j < 8; ++j){
    int k = kb + j;
    float f = (k < 512) ? Wx[k * 2048 + col] : Wh[(k - 512) * 2048 + col];
    pk.v[j] = f2bf(f);
  }
  long long fid = ((w * 4 + q) * 4 + n) * 8 + kk;
  *((uint4*)(wp + fid * 512) + lane) = pk.u;
}

// ---- x -> per-(t,q,kk,m,lane) A-fragment blob (verified) ----
__global__ void k_conv_x(const float* __restrict__ x, uint4* __restrict__ xs){
  int id = blockIdx.x * 256 + threadIdx.x;        // 4,194,304
  int lane = id & 63, m = (id >> 6) & 3, kk = (id >> 8) & 7, q = (id >> 11) & 1, t = id >> 12;
  int row = m * 16 + (lane & 15);
  int k   = q * 256 + kk * 32 + (lane >> 4) * 8;
  const float* src = x + ((long long)row * TT + t) * DD + k;
  union { u16 v[8]; uint4 u; } pk;
#pragma unroll
  for (int j = 0; j < 8; ++j) pk.v[j] = f2bf(src[j]);
  xs[id] = pk.u;
}

// ---- h0 -> fragment blob, buffer 1 (read at t=0). 4096 threads EXACTLY. ----
__global__ void k_conv_h0(const float* __restrict__ h0, u16* __restrict__ hbuf){
  int id = blockIdx.x * 256 + threadIdx.x;        // 4096 total (grid 16)
  int lane = id & 63, m = (id >> 6) & 3, kk = (id >> 8) & 7, kq = (id >> 11) & 1;
  int row = m * 16 + (lane & 15);
  int c   = kq * 256 + kk * 32 + (lane >> 4) * 8;
  const float* src = h0 + row * HH + c;
  union { u16 v[8]; uint4 u; } pk;
#pragma unroll
  for (int j = 0; j < 8; ++j) pk.v[j] = f2bf(src[j]);
  *((uint4*)(hbuf + 32768) + id) = pk.u;
}

// ---- persistent scan: 32 wgs x 256 threads ----
// wave q = K-quarter. q<2: x (no recurrence dep). q>=2: h (polls flags).
// Publication: per-wave. Each wave: h atomic stores -> s_waitcnt vmcnt(0)
// (acks at coherence point) -> lane0 stores flags[w*4+q]=t -> out store.
// Consumers: relaxed poll of all 128 wave-flags (one u64/lane), then relaxed
// atomic h loads. No fences anywhere; L2 stays warm for x/weights.
__launch_bounds__(256, 1)
__global__ void k_lstm(const float* __restrict__ bias_g, float* __restrict__ out,
                       const u16* __restrict__ wp, const uint4* __restrict__ xs,
                       u16* __restrict__ hbuf, int* __restrict__ flags)
{
  __shared__ float part[2][4 * 4160];   // double-buffered [q][row(64)][col(64)] stride 65

  const int tid  = threadIdx.x;
  const int lane = tid & 63;
  const int q    = tid >> 6;
  const int w    = blockIdx.x;
  const int khi  = lane >> 4;
  const int llo  = lane & 15;

  // persistent B fragments: 128 VGPRs
  bf16x8 bfrag[4][8];
  {
    const bf16x8* wpf = (const bf16x8*)wp;
#pragma unroll
    for (int n = 0; n < 4; ++n)
#pragma unroll
      for (int kk = 0; kk < 8; ++kk)
        bfrag[n][kk] = wpf[(((w * 4 + q) * 4 + n) * 8 + kk) * 64 + lane];
  }

  // gate-phase mapping: thread -> (batch row, 4 consecutive h-cols)
  const int grow = tid >> 2;
  const int gjh  = (tid & 3) * 4;
  float bia[4][4];
#pragma unroll
  for (int g = 0; g < 4; ++g)
#pragma unroll
    for (int i = 0; i < 4; ++i) bia[g][i] = bias_g[g * 512 + w * 16 + gjh + i];

  float cst[4] = {0.f, 0.f, 0.f, 0.f};

  // h-store position in fragment blob (u16 units), from (grow, c0=w*16+gjh)
  const int s_kq = w >> 4;
  const int s_kk = (w >> 1) & 7;
  const int s_hi = ((w & 1) * 2 + ((tid & 3) >> 1)) & 3;
  const int s_elem = ((((s_kq * 8 + s_kk) * 4 + (grow >> 4)) * 64
                       + s_hi * 16 + (grow & 15)) * 8) + (tid & 1) * 4;

  const bool is_h = (q >= 2);
  const int  kq   = q & 1;
  int* myflag = flags + w * 4 + q;
  const u64* f64 = (const u64*)flags;

  for (int t = 0; t < TT; ++t){
    f32x4 acc[4][4];
#pragma unroll
    for (int m = 0; m < 4; ++m)
#pragma unroll
      for (int n = 0; n < 4; ++n) acc[m][n] = (f32x4){0.f, 0.f, 0.f, 0.f};

    bf16x8 afrag[8][4];

    if (!is_h){
      // x fragments: plain cached loads (L2-warm)
      const uint4* base = xs + (((long long)(t * 2 + q) * 8) * 4) * 64 + lane;
#pragma unroll
      for (int kk = 0; kk < 8; ++kk)
#pragma unroll
        for (int m = 0; m < 4; ++m)
          afrag[kk][m] = __builtin_bit_cast(bf16x8, base[(kk * 4 + m) * 64]);
    } else {
      // poll all 128 wave-flags: lane l covers flags[2l], flags[2l+1]
      {
        int tgt = t - 1;
        bool ok;
        do {
          u64 v = __hip_atomic_load(f64 + lane, __ATOMIC_RELAXED,
                                    __HIP_MEMORY_SCOPE_AGENT);
          ok = ((int)(u32)v >= tgt) && ((int)(u32)(v >> 32) >= tgt);
        } while (!__all(ok));
        asm volatile("" ::: "memory");
      }
      // h fragments: agent-coherent u64 loads from fragment blob
      const u64* hb = (const u64*)(hbuf + (size_t)(((unsigned)(t - 1)) & 1u) * 32768);
#pragma unroll
      for (int kk = 0; kk < 8; ++kk)
#pragma unroll
        for (int m = 0; m < 4; ++m){
          int fi = (((kq * 8 + kk) * 4 + m) * 64 + lane) * 2;
          u64x2 r;
          r.x = __hip_atomic_load((u64*)(hb + fi),     __ATOMIC_RELAXED, __HIP_MEMORY_SCOPE_AGENT);
          r.y = __hip_atomic_load((u64*)(hb + fi + 1), __ATOMIC_RELAXED, __HIP_MEMORY_SCOPE_AGENT);
          afrag[kk][m] = __builtin_bit_cast(bf16x8, r);
        }
    }

#pragma unroll
    for (int kk = 0; kk < 8; ++kk)
#pragma unroll
      for (int m = 0; m < 4; ++m)
#pragma unroll
        for (int n = 0; n < 4; ++n)
          acc[m][n] = __builtin_amdgcn_mfma_f32_16x16x32_bf16(afrag[kk][m], bfrag[n][kk],
                                                              acc[m][n], 0, 0, 0);

    // K-partials to LDS double buffer
    float* pb = &part[t & 1][0];
#pragma unroll
    for (int m = 0; m < 4; ++m)
#pragma unroll
      for (int n = 0; n < 4; ++n)
#pragma unroll
        for (int r = 0; r < 4; ++r)
          pb[q * 4160 + (m * 16 + khi * 4 + r) * 65 + n * 16 + llo] = acc[m][n][r];
    __syncthreads();   // single barrier per step: partials -> gates

    // gates: each thread 4 h-values, c in registers
    {
      float hv[4]; u16 hb16[4];
#pragma unroll
      for (int i = 0; i < 4; ++i){
        int col = gjh + i;
        float ag[4];
#pragma unroll
        for (int g = 0; g < 4; ++g){
          const float* p = pb + grow * 65 + g * 16 + col;
          ag[g] = p[0] + p[4160] + p[2 * 4160] + p[3 * 4160] + bia[g][i];
        }
        float gi = 1.f / (1.f + __expf(-ag[0]));
        float gf = 1.f / (1.f + __expf(-ag[1]));
        float go = 1.f / (1.f + __expf(-ag[2]));
        float e2 = __expf(-2.f * fabsf(ag[3]));
        float gg = __builtin_copysignf((1.f - e2) / (1.f + e2), ag[3]);
        float c  = gf * cst[i] + gi * gg;
        cst[i] = c;
        float ec = __expf(-2.f * fabsf(c));
        float th = __builtin_copysignf((1.f - ec) / (1.f + ec), c);
        hv[i] = go * th;
        hb16[i] = f2bf(hv[i]);
      }
      // 1) h -> fragment blob (relaxed atomic store, bypasses L2 to L3)
      u64 hword = (u64)hb16[0] | ((u64)hb16[1] << 16) | ((u64)hb16[2] << 32) | ((u64)hb16[3] << 48);
      __hip_atomic_store((u64*)(hbuf + (size_t)(t & 1) * 32768 + s_elem), hword,
                         __ATOMIC_RELAXED, __HIP_MEMORY_SCOPE_AGENT);
      // 2) wait only the h store (out store not yet issued)
      asm volatile("s_waitcnt vmcnt(0)" ::: "memory");
      // 3) per-wave flag publish
      if (lane == 0)
        __hip_atomic_store(myflag, t, __ATOMIC_RELAXED, __HIP_MEMORY_SCOPE_AGENT);
      // 4) out store off the critical path
      float4 ov = make_float4(hv[0], hv[1], hv[2], hv[3]);
      *(float4*)(out + ((long long)grow * TT + t) * HH + w * 16 + gjh) = ov;
    }
    // no end-of-step barrier: part is double-buffered; hbuf protected by poll
  }
}

extern "C" void kernel_launch(void* const* d_in, const int* in_sizes, int n_in,
                              void* d_out, int out_size, void* d_ws, size_t ws_size,
                              hipStream_t stream){
  const float* x  = (const float*)d_in[0];
  const float* h0 = (const float*)d_in[1];
  const float* Wx = (const float*)d_in[2];
  const float* Wh = (const float*)d_in[3];
  const float* b  = (const float*)d_in[4];
  float* out = (float*)d_out;

  unsigned char* ws = (unsigned char*)d_ws;
  u16*  wp    = (u16*)(ws + OFF_WPACK);
  uint4* xs   = (uint4*)(ws + OFF_XS);
  u16*  hb    = (u16*)(ws + OFF_HBUF);
  int*  flags = (int*)(ws + OFF_FLAGS);

  hipLaunchKernelGGL(k_init_flags, dim3(1),     dim3(128), 0, stream, flags);
  hipLaunchKernelGGL(k_pack_w,     dim3(1024),  dim3(256), 0, stream, Wx, Wh, wp);
  hipLaunchKernelGGL(k_conv_x,     dim3(16384), dim3(256), 0, stream, x, xs);
  hipLaunchKernelGGL(k_conv_h0,    dim3(16),    dim3(256), 0, stream, h0, hb);
  hipLaunchKernelGGL(k_lstm,       dim3(32),    dim3(256), 0, stream, b, out, wp, xs, hb, flags);
}

// Round 5
// 3633.542 us; speedup vs baseline: 1.6641x; 1.6641x over previous
//
#include <hip/hip_runtime.h>
#include <hip/hip_bf16.h>
#include <stdint.h>

#define TT 1024
#define DD 512
#define HH 512

typedef short bf16x8 __attribute__((ext_vector_type(8)));
typedef float f32x4 __attribute__((ext_vector_type(4)));
typedef unsigned long long u64;
typedef unsigned int u32;
typedef unsigned short u16;

// ---- workspace layout (bytes) ----
// wpack: per (p<32, q<4, G<4, kk<8) 64-lane uint4 frags = 4 MiB (shared by all 4 groups)
#define OFF_WPACK 0ull
#define SZ_WPACK  (32ull*4*4*8*1024)
// xs: per (t, g<4, q<2, kk<8) 64-lane uint4 A-frags = 64 MiB
#define OFF_XS    (OFF_WPACK + SZ_WPACK)
#define SZ_XS     (1024ull*4*2*8*1024)
// hbufs: [group 4][buf 4][4096 u64]  (u64 = tag<<32 | h(2c+1)<<16 | h(2c)) = 512 KiB
#define OFF_HB    (OFF_XS + SZ_XS)
#define SZ_HB     (4ull*4*4096*8)

__device__ __forceinline__ u16 f2bf(float f){
  u32 u = __builtin_bit_cast(u32, f);
  u32 r = (u + 0x7fffu + ((u >> 16) & 1u)) >> 16;   // RNE
  return (u16)r;
}

// ---- clear all hbuf tags every launch (no cross-replay state) ----
__global__ void k_clear(u64* hb){
  int id = blockIdx.x * 256 + threadIdx.x;          // 65536
  hb[id] = 0x8000000000000000ull;                   // tag never matches any t-1
}

// ---- pack Wcat=[Wx;Wh] into B-frags: col = G*512 + p*16 + (lane&15),
//      k = q*256 + kk*32 + (lane>>4)*8 + j ----
__global__ void k_pack_w(const float* __restrict__ Wx, const float* __restrict__ Wh,
                         u16* __restrict__ wp){
  int id = blockIdx.x * 256 + threadIdx.x;          // 262144
  int lane = id & 63;
  int kk = (id >> 6) & 7, G = (id >> 9) & 3, q = (id >> 11) & 3, p = id >> 13;
  int col = G * 512 + p * 16 + (lane & 15);
  int kb  = q * 256 + kk * 32 + (lane >> 4) * 8;
  union { u16 v[8]; uint4 u; } pk;
#pragma unroll
  for (int j = 0; j < 8; ++j){
    int k = kb + j;
    float f = (k < 512) ? Wx[k * 2048 + col] : Wh[(k - 512) * 2048 + col];
    pk.v[j] = f2bf(f);
  }
  long long fid = ((p * 4 + q) * 4 + G) * 8 + kk;
  *((uint4*)wp + fid * 64 + lane) = pk.u;
}

// ---- x -> per-(t,g,q,kk) M=16 A-frags: row = g*16+(lane&15),
//      k = q*256 + kk*32 + (lane>>4)*8 + j ----
__global__ void k_conv_x(const float* __restrict__ x, uint4* __restrict__ xs){
  int id = blockIdx.x * 256 + threadIdx.x;          // 4,194,304
  int lane = id & 63, kk = (id >> 6) & 7, q = (id >> 9) & 1, g = (id >> 10) & 3, t = id >> 12;
  int row = g * 16 + (lane & 15);
  int k   = q * 256 + kk * 32 + (lane >> 4) * 8;
  const float* src = x + ((long long)row * TT + t) * DD + k;
  union { u16 v[8]; uint4 u; } pk;
#pragma unroll
  for (int j = 0; j < 8; ++j) pk.v[j] = f2bf(src[j]);
  xs[id] = pk.u;
}

// ---- h0 -> tagged words in buf 3, tag = 0xFFFFFFFF (= (u32)(0-1)) ----
__global__ void k_conv_h0(const float* __restrict__ h0, u64* __restrict__ hb){
  int id = blockIdx.x * 256 + threadIdx.x;          // 16384
  int row = id & 15, cp = (id >> 4) & 255, g = id >> 12;
  u32 v0 = f2bf(h0[(g * 16 + row) * HH + 2 * cp]);
  u32 v1 = f2bf(h0[(g * 16 + row) * HH + 2 * cp + 1]);
  hb[((size_t)g * 4 + 3) * 4096 + cp * 16 + row] =
      (0xFFFFFFFFull << 32) | ((u64)v1 << 16) | v0;
}

// ---- persistent scan: 128 wgs (4 groups x 32) x 256 threads ----
// wg w: g=w>>5 (batch rows 16g..), p=w&31 (h-cols 16p..). wave q = K-quarter:
// q<2 x-half (free-running), q>=2 h-half (polls tagged data words).
// Publish = fire-and-forget tagged u64 stores; no acks, no flags, no fences.
__launch_bounds__(256, 1)
__global__ void k_lstm(const float* __restrict__ bias_g, float* __restrict__ out,
                       const u16* __restrict__ wp, const uint4* __restrict__ xs,
                       u64* __restrict__ hbufs)
{
  __shared__ float part[2][4096];    // [buf][q*1024 + G*256 + row*16 + col]

  const int tid  = threadIdx.x;
  const int lane = tid & 63;
  const int q    = tid >> 6;
  const int w    = blockIdx.x;
  const int g    = w >> 5;
  const int p    = w & 31;
  const int khi  = lane >> 4;
  const int llo  = lane & 15;

  // persistent B fragments: 32 frags = 128 VGPRs
  bf16x8 bfrag[4][8];
  {
    const bf16x8* wpf = (const bf16x8*)wp;
#pragma unroll
    for (int G = 0; G < 4; ++G)
#pragma unroll
      for (int kk = 0; kk < 8; ++kk)
        bfrag[G][kk] = wpf[(((p * 4 + q) * 4 + G) * 8 + kk) * 64 + lane];
  }

  // gate mapping: thread -> (row_g = batch row in group, col_g = h-col in wg)
  const int row_g = tid >> 4;
  const int col_g = tid & 15;
  float bia[4];
#pragma unroll
  for (int G = 0; G < 4; ++G) bia[G] = bias_g[G * 512 + p * 16 + col_g];

  float cs = 0.f;                    // cell state, 1 per thread

  u64* gb = hbufs + (size_t)g * 4 * 4096;          // own group's buffers
  const int wbase = (((q & 1) * 128 + khi * 4) * 16) + llo;  // consumer word base
  const bool storer = ((col_g & 1) == 0);
  const int swidx = (p * 8 + (col_g >> 1)) * 16 + row_g;     // producer word idx
  float* outp = out + ((size_t)(g * 16 + row_g) * TT) * HH + p * 16 + col_g;

  for (int t = 0; t < TT; ++t){
    f32x4 acc[4];
#pragma unroll
    for (int n = 0; n < 4; ++n) acc[n] = (f32x4){0.f, 0.f, 0.f, 0.f};

    if (q < 2){
      // x K-half: plain cached frag loads (L2/L3-warm), never blocks on recurrence
      const uint4* xb = xs + ((((size_t)t * 4 + g) * 2 + q) * 8) * 64 + lane;
#pragma unroll
      for (int kk = 0; kk < 8; ++kk){
        bf16x8 av = __builtin_bit_cast(bf16x8, xb[kk * 64]);
#pragma unroll
        for (int n = 0; n < 4; ++n)
          acc[n] = __builtin_amdgcn_mfma_f32_16x16x32_bf16(av, bfrag[n][kk], acc[n], 0, 0, 0);
      }
    } else {
      // h K-half: poll tagged data words of h(t-1); discovery IS the load
      const u64* bb = gb + (size_t)((t + 3) & 3) * 4096;
      const u32 tg = (u32)(t - 1);
      u64 wv[32];
#pragma unroll
      for (int j = 0; j < 32; ++j){
        int kk = j >> 2, jj = j & 3;
        wv[j] = __hip_atomic_load(bb + wbase + kk * 256 + jj * 16,
                                  __ATOMIC_RELAXED, __HIP_MEMORY_SCOPE_AGENT);
      }
      for (;;){
        bool ok = true;
#pragma unroll
        for (int j = 0; j < 32; ++j) ok &= ((u32)(wv[j] >> 32) == tg);
        if (__all(ok)) break;
        __builtin_amdgcn_s_sleep(1);
#pragma unroll
        for (int j = 0; j < 32; ++j){
          int kk = j >> 2, jj = j & 3;
          if ((u32)(wv[j] >> 32) != tg)
            wv[j] = __hip_atomic_load(bb + wbase + kk * 256 + jj * 16,
                                      __ATOMIC_RELAXED, __HIP_MEMORY_SCOPE_AGENT);
        }
      }
      asm volatile("" ::: "memory");
#pragma unroll
      for (int kk = 0; kk < 8; ++kk){
        union { u32 d[4]; bf16x8 v; } af;
#pragma unroll
        for (int jj = 0; jj < 4; ++jj) af.d[jj] = (u32)wv[kk * 4 + jj];
#pragma unroll
        for (int n = 0; n < 4; ++n)
          acc[n] = __builtin_amdgcn_mfma_f32_16x16x32_bf16(af.v, bfrag[n][kk], acc[n], 0, 0, 0);
      }
    }

    // K-partials to double-buffered LDS
    float* pb = &part[t & 1][0];
#pragma unroll
    for (int n = 0; n < 4; ++n)
#pragma unroll
      for (int r = 0; r < 4; ++r)
        pb[q * 1024 + n * 256 + (khi * 4 + r) * 16 + llo] = acc[n][r];
    __syncthreads();   // single barrier per step

    // gates: 1 h-value per thread
    {
      const float* pr = pb + row_g * 16 + col_g;
      float aG[4];
#pragma unroll
      for (int G = 0; G < 4; ++G)
        aG[G] = pr[G * 256] + pr[1024 + G * 256] + pr[2048 + G * 256]
              + pr[3072 + G * 256] + bia[G];
      float gi = 1.f / (1.f + __expf(-aG[0]));
      float gf = 1.f / (1.f + __expf(-aG[1]));
      float go = 1.f / (1.f + __expf(-aG[2]));
      float e2 = __expf(-2.f * fabsf(aG[3]));
      float gg = __builtin_copysignf((1.f - e2) / (1.f + e2), aG[3]);
      float c  = gf * cs + gi * gg;
      cs = c;
      float ec = __expf(-2.f * fabsf(c));
      float th = __builtin_copysignf((1.f - ec) / (1.f + ec), c);
      float h  = go * th;

      // publish: tagged u64 (2 h-values via lane shuffle), fire-and-forget
      u32 hb16 = f2bf(h);
      u32 pv   = __shfl_down(hb16, 1);
      if (storer)
        __hip_atomic_store(gb + (size_t)(t & 3) * 4096 + swidx,
                           ((u64)(u32)t << 32) | ((u64)pv << 16) | hb16,
                           __ATOMIC_RELAXED, __HIP_MEMORY_SCOPE_AGENT);
      // output (plain store, off critical path)
      outp[(size_t)t * HH] = h;
    }
  }
}

extern "C" void kernel_launch(void* const* d_in, const int* in_sizes, int n_in,
                              void* d_out, int out_size, void* d_ws, size_t ws_size,
                              hipStream_t stream){
  const float* x  = (const float*)d_in[0];
  const float* h0 = (const float*)d_in[1];
  const float* Wx = (const float*)d_in[2];
  const float* Wh = (const float*)d_in[3];
  const float* b  = (const float*)d_in[4];
  float* out = (float*)d_out;

  unsigned char* ws = (unsigned char*)d_ws;
  u16*   wp = (u16*)(ws + OFF_WPACK);
  uint4* xs = (uint4*)(ws + OFF_XS);
  u64*   hb = (u64*)(ws + OFF_HB);

  hipLaunchKernelGGL(k_clear,   dim3(256),   dim3(256), 0, stream, hb);
  hipLaunchKernelGGL(k_pack_w,  dim3(1024),  dim3(256), 0, stream, Wx, Wh, wp);
  hipLaunchKernelGGL(k_conv_x,  dim3(16384), dim3(256), 0, stream, x, xs);
  hipLaunchKernelGGL(k_conv_h0, dim3(64),    dim3(256), 0, stream, h0, hb);
  hipLaunchKernelGGL(k_lstm,    dim3(128),   dim3(256), 0, stream, b, out, wp, xs, hb);
}